// Round 3
// baseline (477.788 us; speedup 1.0000x reference)
//
#include <hip/hip_runtime.h>

#define DIN 48
#define DOUT 16
#define DC 32      // combined output dims: [mu(16) | logstd(16)]
#define BSH 7      // bucket shift: 128 nodes per bucket
#define BNODES 128
#define NBP 1024   // padded bucket count (power of 2, >= nb)
#define EPB 8192   // edges per binning block
#define TPB_BIN 1024

typedef unsigned int uint;

// ---------- small utility kernels ----------

__global__ void k_zero_cnt(int* __restrict__ cnt, int n) {
    int i = blockIdx.x * blockDim.x + threadIdx.x;
    if (i < n) cnt[i] = 0;
}

__global__ void k_hist(const int* __restrict__ dst, int* __restrict__ cnt, int e_cnt) {
    int e = blockIdx.x * blockDim.x + threadIdx.x;
    if (e < e_cnt) atomicAdd(&cnt[dst[e]], 1);
}

// bucket sums from per-node counts: one block (128 threads) per bucket
__global__ void k_bsum(const int* __restrict__ cnt, int* __restrict__ bsum, int n) {
    int b = blockIdx.x, t = threadIdx.x;
    int i = (b << BSH) + t;
    int v = (i < n) ? cnt[i] : 0;
    v += __shfl_down(v, 32);
    v += __shfl_down(v, 16);
    v += __shfl_down(v, 8);
    v += __shfl_down(v, 4);
    v += __shfl_down(v, 2);
    v += __shfl_down(v, 1);
    __shared__ int ws2[2];
    if ((t & 63) == 0) ws2[t >> 6] = v;
    __syncthreads();
    if (t == 0) bsum[b] = ws2[0] + ws2[1];
}

// single-block exclusive scan of <=1024 bucket sums; also zero bfill
__global__ void k_bscan(const int* __restrict__ bsum, int* __restrict__ boffs,
                        int* __restrict__ bfill, int nb) {
    __shared__ int sd[NBP];
    int t = threadIdx.x;
    int v = (t < nb) ? bsum[t] : 0;
    sd[t] = v;
    __syncthreads();
#pragma unroll
    for (int off = 1; off < NBP; off <<= 1) {
        int x = (t >= off) ? sd[t - off] : 0;
        __syncthreads();
        sd[t] += x;
        __syncthreads();
    }
    if (t < nb) { boffs[t] = sd[t] - v; bfill[t] = 0; }
}

// ---------- projection (proj_scaled = dinv * x@[Wmu|Wls]; out = self term) ----------

__global__ void k_proj2(const float* __restrict__ x,
                        const float* __restrict__ Wmu, const float* __restrict__ bmu,
                        const float* __restrict__ Wls, const float* __restrict__ bls,
                        const int* __restrict__ cnt, float* __restrict__ dinv,
                        float* __restrict__ proj, float* __restrict__ out, int n) {
    __shared__ float Ws[DIN * DC];
    __shared__ float bs[DC];
    int t = threadIdx.x;
    for (int idx = t; idx < DIN * DC; idx += blockDim.x) {
        int k = idx >> 5, j = idx & 31;
        Ws[idx] = (j < DOUT) ? Wmu[k * DOUT + j] : Wls[k * DOUT + (j - DOUT)];
    }
    if (t < DC) bs[t] = (t < DOUT) ? bmu[t] : bls[t - DOUT];
    __syncthreads();

    int i = blockIdx.x * blockDim.x + t;
    if (i >= n) return;

    float xr[DIN];
    const float4* xp = reinterpret_cast<const float4*>(x + (size_t)i * DIN);
#pragma unroll
    for (int q = 0; q < DIN / 4; ++q) {
        float4 v = xp[q];
        xr[4 * q + 0] = v.x; xr[4 * q + 1] = v.y;
        xr[4 * q + 2] = v.z; xr[4 * q + 3] = v.w;
    }

    float acc[DC];
#pragma unroll
    for (int j = 0; j < DC; ++j) acc[j] = 0.0f;
#pragma unroll 4
    for (int k = 0; k < DIN; ++k) {
        float xv = xr[k];
#pragma unroll
        for (int j = 0; j < DC; ++j) acc[j] += xv * Ws[k * DC + j];
    }

    float dv = rsqrtf(1.0f + (float)cnt[i]);
    dinv[i] = dv;

    float4* pp = reinterpret_cast<float4*>(proj + (size_t)i * DC);
#pragma unroll
    for (int q = 0; q < DC / 4; ++q) {
        float4 v;
        v.x = dv * acc[4 * q + 0]; v.y = dv * acc[4 * q + 1];
        v.z = dv * acc[4 * q + 2]; v.w = dv * acc[4 * q + 3];
        pp[q] = v;
    }

    float d2 = dv * dv;
    float* omu = out + (size_t)i * DOUT;
    float* ols = out + (size_t)n * DOUT + (size_t)i * DOUT;
#pragma unroll
    for (int j = 0; j < DOUT; ++j) omu[j] = bs[j] + d2 * acc[j];
#pragma unroll
    for (int j = 0; j < DOUT; ++j) ols[j] = bs[DOUT + j] + d2 * acc[DOUT + j];
}

// ---------- binning: stage edges bucket-sorted in LDS, write contiguous runs ----------

__global__ __launch_bounds__(TPB_BIN) void k_bin(
        const int* __restrict__ src, const int* __restrict__ dst,
        const int* __restrict__ boffs, int* __restrict__ bfill,
        uint* __restrict__ ebuf, int e_cnt, int nb) {
    __shared__ uint stageV[EPB];              // 32KB (also scan temp)
    __shared__ unsigned short stageB[EPB];    // 16KB
    __shared__ int hist[NBP];                 // 4KB (reused as local fill)
    __shared__ int lofs[NBP];                 // 4KB
    __shared__ int gbase[NBP];                // 4KB

    int t = threadIdx.x;
    int e0 = blockIdx.x * EPB;
    int ec = min(EPB, e_cnt - e0);

    hist[t] = 0;
    __syncthreads();
    // pass A: local histogram
    for (int k = t; k < ec; k += TPB_BIN) atomicAdd(&hist[dst[e0 + k] >> BSH], 1);
    __syncthreads();
    // exclusive scan of hist -> lofs (stageV as temp)
    {
        int v = hist[t];
        uint* sd = stageV;
        sd[t] = (uint)v;
        __syncthreads();
#pragma unroll
        for (int off = 1; off < NBP; off <<= 1) {
            uint x = (t >= off) ? sd[t - off] : 0u;
            __syncthreads();
            sd[t] += x;
            __syncthreads();
        }
        lofs[t] = (int)sd[t] - v;
    }
    // reserve global space: one atomic per nonempty bucket
    if (t < nb) {
        int h = hist[t];
        if (h > 0) gbase[t] = atomicAdd(&bfill[t], h);
    }
    __syncthreads();
    hist[t] = 0;  // becomes local fill counter
    __syncthreads();
    // pass B: stage packed edges in bucket order
    for (int k = t; k < ec; k += TPB_BIN) {
        int d = dst[e0 + k], s = src[e0 + k];
        int b = d >> BSH;
        int p = atomicAdd(&hist[b], 1);
        int idx = lofs[b] + p;
        stageV[idx] = ((uint)(d & (BNODES - 1)) << 17) | (uint)s;
        stageB[idx] = (unsigned short)b;
    }
    __syncthreads();
    // pass C: contiguous-run copy out
    for (int i = t; i < ec; i += TPB_BIN) {
        int b = stageB[i];
        int gpos = boffs[b] + gbase[b] + (i - lofs[b]);
        ebuf[gpos] = stageV[i];
    }
}

// ---------- aggregation: one block per bucket, LDS accumulator, no global atomics ----------

__global__ __launch_bounds__(256) void k_agg2(
        const uint* __restrict__ ebuf, const int* __restrict__ boffs,
        const float* __restrict__ dinv, const float* __restrict__ proj,
        float* __restrict__ out, int n, int e_cnt, int nb) {
    __shared__ float acc[BNODES * DC];  // 16KB
    int t = threadIdx.x;
    int b = blockIdx.x;
    for (int i = t; i < BNODES * DC; i += 256) acc[i] = 0.0f;
    __syncthreads();

    int start = boffs[b];
    int end = (b + 1 < nb) ? boffs[b + 1] : e_cnt;
    int lane = t & 31, grp = t >> 5;
    for (int k = start + grp; k < end; k += 8) {
        uint pk = ebuf[k];
        int s = (int)(pk & 0x1FFFFu);
        int local = (int)(pk >> 17);
        float v = proj[((size_t)s << 5) + lane];  // 128B line per edge, coalesced
        atomicAdd(&acc[(local << 5) + lane], v);  // ds_add_f32, bank==lane: conflict-free
    }
    __syncthreads();

    int base = b << BSH;
    for (int i = t; i < BNODES * DC; i += 256) {
        int ln = i >> 5, j = i & 31;
        int d = base + ln;
        if (d < n) {
            float add = dinv[d] * acc[i];
            if (j < 16) out[(size_t)d * DOUT + j] += add;
            else        out[(size_t)n * DOUT + (size_t)d * DOUT + (j - 16)] += add;
        }
    }
}

// ---------- fallback (round-1 atomic) path ----------

__global__ void k_init_deg(float* __restrict__ deg, int n) {
    int i = blockIdx.x * blockDim.x + threadIdx.x;
    if (i < n) deg[i] = 1.0f;
}

__global__ void k_count(const int* __restrict__ dst, float* __restrict__ deg, int e_cnt) {
    int e = blockIdx.x * blockDim.x + threadIdx.x;
    if (e < e_cnt) unsafeAtomicAdd(&deg[dst[e]], 1.0f);
}

__global__ void k_projF(const float* __restrict__ x,
                        const float* __restrict__ Wmu, const float* __restrict__ bmu,
                        const float* __restrict__ Wls, const float* __restrict__ bls,
                        float* __restrict__ deg_dinv, float* __restrict__ proj,
                        float* __restrict__ out, int n) {
    __shared__ float Ws[DIN * DC];
    __shared__ float bs[DC];
    int t = threadIdx.x;
    for (int idx = t; idx < DIN * DC; idx += blockDim.x) {
        int k = idx >> 5, j = idx & 31;
        Ws[idx] = (j < DOUT) ? Wmu[k * DOUT + j] : Wls[k * DOUT + (j - DOUT)];
    }
    if (t < DC) bs[t] = (t < DOUT) ? bmu[t] : bls[t - DOUT];
    __syncthreads();
    int i = blockIdx.x * blockDim.x + t;
    if (i >= n) return;
    float xr[DIN];
    const float4* xp = reinterpret_cast<const float4*>(x + (size_t)i * DIN);
#pragma unroll
    for (int q = 0; q < DIN / 4; ++q) {
        float4 v = xp[q];
        xr[4 * q + 0] = v.x; xr[4 * q + 1] = v.y;
        xr[4 * q + 2] = v.z; xr[4 * q + 3] = v.w;
    }
    float acc[DC];
#pragma unroll
    for (int j = 0; j < DC; ++j) acc[j] = 0.0f;
#pragma unroll 4
    for (int k = 0; k < DIN; ++k) {
        float xv = xr[k];
#pragma unroll
        for (int j = 0; j < DC; ++j) acc[j] += xv * Ws[k * DC + j];
    }
    float dv = rsqrtf(deg_dinv[i]);
    deg_dinv[i] = dv;
    float d2 = dv * dv;
    float4* pp = reinterpret_cast<float4*>(proj + (size_t)i * DC);
#pragma unroll
    for (int q = 0; q < DC / 4; ++q) {
        float4 v;
        v.x = acc[4 * q + 0]; v.y = acc[4 * q + 1];
        v.z = acc[4 * q + 2]; v.w = acc[4 * q + 3];
        pp[q] = v;
    }
    float* omu = out + (size_t)i * DOUT;
    float* ols = out + (size_t)n * DOUT + (size_t)i * DOUT;
#pragma unroll
    for (int j = 0; j < DOUT; ++j) omu[j] = bs[j] + d2 * acc[j];
#pragma unroll
    for (int j = 0; j < DOUT; ++j) ols[j] = bs[DOUT + j] + d2 * acc[DOUT + j];
}

__global__ void k_scatterF(const int* __restrict__ src, const int* __restrict__ dst,
                           const float* __restrict__ dinv, const float* __restrict__ proj,
                           float* __restrict__ out, int e_cnt, int n) {
    long long gid = (long long)blockIdx.x * blockDim.x + threadIdx.x;
    int e = (int)(gid >> 5);
    int j = (int)(gid & 31);
    if (e >= e_cnt) return;
    int s = src[e], d = dst[e];
    float norm = dinv[s] * dinv[d];
    float v = norm * proj[(size_t)s * DC + j];
    float* o = (j < DOUT) ? (out + (size_t)d * DOUT + j)
                          : (out + (size_t)n * DOUT + (size_t)d * DOUT + (j - DOUT));
    unsafeAtomicAdd(o, v);
}

// ---------- launch ----------

extern "C" void kernel_launch(void* const* d_in, const int* in_sizes, int n_in,
                              void* d_out, int out_size, void* d_ws, size_t ws_size,
                              hipStream_t stream) {
    const float* x   = (const float*)d_in[0];
    const int*   ei  = (const int*)d_in[1];
    const float* Wmu = (const float*)d_in[2];
    const float* bmu = (const float*)d_in[3];
    const float* Wls = (const float*)d_in[4];
    const float* bls = (const float*)d_in[5];
    float* out = (float*)d_out;

    int n = in_sizes[0] / DIN;       // 100000
    int e_cnt = in_sizes[1] / 2;     // 1600000
    const int* src = ei;
    const int* dst = ei + e_cnt;

    int nb = (n + BNODES - 1) >> BSH;   // 782 buckets
    bool pack_ok = (n <= (1 << 17));

    size_t need = (size_t)n * 4           /* cnt  */
                + (size_t)n * 4           /* dinv */
                + (size_t)n * DC * 4      /* proj */
                + (size_t)NBP * 4 * 3     /* bsum, boffs, bfill */
                + (size_t)e_cnt * 4;      /* ebuf */

    int nblk = (n + 255) / 256;
    int eblk = (e_cnt + 255) / 256;

    if (nb <= NBP && pack_ok && ws_size >= need) {
        char* w = (char*)d_ws;
        int*   cnt   = (int*)w;    w += (size_t)n * 4;
        float* dinv  = (float*)w;  w += (size_t)n * 4;
        float* proj  = (float*)w;  w += (size_t)n * DC * 4;
        int*   bsum  = (int*)w;    w += NBP * 4;
        int*   boffs = (int*)w;    w += NBP * 4;
        int*   bfill = (int*)w;    w += NBP * 4;
        uint*  ebuf  = (uint*)w;

        k_zero_cnt<<<nblk, 256, 0, stream>>>(cnt, n);
        k_hist<<<eblk, 256, 0, stream>>>(dst, cnt, e_cnt);
        k_proj2<<<nblk, 256, 0, stream>>>(x, Wmu, bmu, Wls, bls, cnt, dinv, proj, out, n);
        k_bsum<<<nb, 128, 0, stream>>>(cnt, bsum, n);
        k_bscan<<<1, NBP, 0, stream>>>(bsum, boffs, bfill, nb);
        int binblk = (e_cnt + EPB - 1) / EPB;
        k_bin<<<binblk, TPB_BIN, 0, stream>>>(src, dst, boffs, bfill, ebuf, e_cnt, nb);
        k_agg2<<<nb, 256, 0, stream>>>(ebuf, boffs, dinv, proj, out, n, e_cnt, nb);
    } else {
        float* deg  = (float*)d_ws;
        float* proj = deg + n;
        k_init_deg<<<nblk, 256, 0, stream>>>(deg, n);
        k_count<<<eblk, 256, 0, stream>>>(dst, deg, e_cnt);
        k_projF<<<nblk, 256, 0, stream>>>(x, Wmu, bmu, Wls, bls, deg, proj, out, n);
        long long tasks = (long long)e_cnt * DC;
        k_scatterF<<<(int)((tasks + 255) / 256), 256, 0, stream>>>(src, dst, deg, proj, out, e_cnt, n);
    }
}

// Round 4
// 172.292 us; speedup vs baseline: 2.7731x; 2.7731x over previous
//
#include <hip/hip_runtime.h>

#define DIN 48
#define DOUT 16
#define DC 32      // combined output dims: [mu(16) | logstd(16)]
#define BSH 7      // bucket shift: 128 nodes per bucket
#define BNODES 128
#define NBP 1024   // padded bucket count (power of 2, >= nb)
#define EPB 8192   // edges per binning block
#define TPB_BIN 1024
#define CAP 4096   // max staged edges per bucket in k_sortb (mean 2048, +45 sigma)

typedef unsigned int uint;

// ---------- small utility kernels ----------

__global__ void k_zero_cnt(int* __restrict__ cnt, int n) {
    int i = blockIdx.x * blockDim.x + threadIdx.x;
    if (i < n) cnt[i] = 0;
}

__global__ void k_hist(const int* __restrict__ dst, int* __restrict__ cnt, int e_cnt) {
    int e = blockIdx.x * blockDim.x + threadIdx.x;
    if (e < e_cnt) atomicAdd(&cnt[dst[e]], 1);
}

// bucket sums from per-node counts: one block (128 threads) per bucket
__global__ void k_bsum(const int* __restrict__ cnt, int* __restrict__ bsum, int n) {
    int b = blockIdx.x, t = threadIdx.x;
    int i = (b << BSH) + t;
    int v = (i < n) ? cnt[i] : 0;
    v += __shfl_down(v, 32);
    v += __shfl_down(v, 16);
    v += __shfl_down(v, 8);
    v += __shfl_down(v, 4);
    v += __shfl_down(v, 2);
    v += __shfl_down(v, 1);
    __shared__ int ws2[2];
    if ((t & 63) == 0) ws2[t >> 6] = v;
    __syncthreads();
    if (t == 0) bsum[b] = ws2[0] + ws2[1];
}

// single-block exclusive scan of <=1024 bucket sums; also zero bfill
__global__ void k_bscan(const int* __restrict__ bsum, int* __restrict__ boffs,
                        int* __restrict__ bfill, int nb) {
    __shared__ int sd[NBP];
    int t = threadIdx.x;
    int v = (t < nb) ? bsum[t] : 0;
    sd[t] = v;
    __syncthreads();
#pragma unroll
    for (int off = 1; off < NBP; off <<= 1) {
        int x = (t >= off) ? sd[t - off] : 0;
        __syncthreads();
        sd[t] += x;
        __syncthreads();
    }
    if (t < nb) { boffs[t] = sd[t] - v; bfill[t] = 0; }
}

// ---------- projection (proj_scaled = dinv * x@[Wmu|Wls]; out = self term) ----------

__global__ void k_proj2(const float* __restrict__ x,
                        const float* __restrict__ Wmu, const float* __restrict__ bmu,
                        const float* __restrict__ Wls, const float* __restrict__ bls,
                        const int* __restrict__ cnt, float* __restrict__ dinv,
                        float* __restrict__ proj, float* __restrict__ out, int n) {
    __shared__ float Ws[DIN * DC];
    __shared__ float bs[DC];
    int t = threadIdx.x;
    for (int idx = t; idx < DIN * DC; idx += blockDim.x) {
        int k = idx >> 5, j = idx & 31;
        Ws[idx] = (j < DOUT) ? Wmu[k * DOUT + j] : Wls[k * DOUT + (j - DOUT)];
    }
    if (t < DC) bs[t] = (t < DOUT) ? bmu[t] : bls[t - DOUT];
    __syncthreads();

    int i = blockIdx.x * blockDim.x + t;
    if (i >= n) return;

    float xr[DIN];
    const float4* xp = reinterpret_cast<const float4*>(x + (size_t)i * DIN);
#pragma unroll
    for (int q = 0; q < DIN / 4; ++q) {
        float4 v = xp[q];
        xr[4 * q + 0] = v.x; xr[4 * q + 1] = v.y;
        xr[4 * q + 2] = v.z; xr[4 * q + 3] = v.w;
    }

    float acc[DC];
#pragma unroll
    for (int j = 0; j < DC; ++j) acc[j] = 0.0f;
#pragma unroll 4
    for (int k = 0; k < DIN; ++k) {
        float xv = xr[k];
#pragma unroll
        for (int j = 0; j < DC; ++j) acc[j] += xv * Ws[k * DC + j];
    }

    float dv = rsqrtf(1.0f + (float)cnt[i]);
    dinv[i] = dv;

    float4* pp = reinterpret_cast<float4*>(proj + (size_t)i * DC);
#pragma unroll
    for (int q = 0; q < DC / 4; ++q) {
        float4 v;
        v.x = dv * acc[4 * q + 0]; v.y = dv * acc[4 * q + 1];
        v.z = dv * acc[4 * q + 2]; v.w = dv * acc[4 * q + 3];
        pp[q] = v;
    }

    float d2 = dv * dv;
    float* omu = out + (size_t)i * DOUT;
    float* ols = out + (size_t)n * DOUT + (size_t)i * DOUT;
#pragma unroll
    for (int j = 0; j < DOUT; ++j) omu[j] = bs[j] + d2 * acc[j];
#pragma unroll
    for (int j = 0; j < DOUT; ++j) ols[j] = bs[DOUT + j] + d2 * acc[DOUT + j];
}

// ---------- binning: stage edges bucket-sorted in LDS, write contiguous runs ----------

__global__ __launch_bounds__(TPB_BIN) void k_bin(
        const int* __restrict__ src, const int* __restrict__ dst,
        const int* __restrict__ boffs, int* __restrict__ bfill,
        uint* __restrict__ ebuf, int e_cnt, int nb) {
    __shared__ uint stageV[EPB];              // 32KB (also scan temp)
    __shared__ unsigned short stageB[EPB];    // 16KB
    __shared__ int hist[NBP];                 // 4KB (reused as local fill)
    __shared__ int lofs[NBP];                 // 4KB
    __shared__ int gbase[NBP];                // 4KB

    int t = threadIdx.x;
    int e0 = blockIdx.x * EPB;
    int ec = min(EPB, e_cnt - e0);

    hist[t] = 0;
    __syncthreads();
    for (int k = t; k < ec; k += TPB_BIN) atomicAdd(&hist[dst[e0 + k] >> BSH], 1);
    __syncthreads();
    {
        int v = hist[t];
        uint* sd = stageV;
        sd[t] = (uint)v;
        __syncthreads();
#pragma unroll
        for (int off = 1; off < NBP; off <<= 1) {
            uint x = (t >= off) ? sd[t - off] : 0u;
            __syncthreads();
            sd[t] += x;
            __syncthreads();
        }
        lofs[t] = (int)sd[t] - v;
    }
    if (t < nb) {
        int h = hist[t];
        if (h > 0) gbase[t] = atomicAdd(&bfill[t], h);
    }
    __syncthreads();
    hist[t] = 0;
    __syncthreads();
    for (int k = t; k < ec; k += TPB_BIN) {
        int d = dst[e0 + k], s = src[e0 + k];
        int b = d >> BSH;
        int p = atomicAdd(&hist[b], 1);
        int idx = lofs[b] + p;
        stageV[idx] = ((uint)(d & (BNODES - 1)) << 17) | (uint)s;
        stageB[idx] = (unsigned short)b;
    }
    __syncthreads();
    for (int i = t; i < ec; i += TPB_BIN) {
        int b = stageB[i];
        int gpos = boffs[b] + gbase[b] + (i - lofs[b]);
        ebuf[gpos] = stageV[i];
    }
}

// ---------- per-bucket node sort: bucket CSR -> node CSR, coalesced ----------

__global__ __launch_bounds__(256) void k_sortb(
        const uint* __restrict__ ebuf, const int* __restrict__ boffs,
        int* __restrict__ node_offs, int* __restrict__ esrc,
        int n, int e_cnt, int nb) {
    __shared__ uint stage_in[CAP];   // 16KB raw packed entries
    __shared__ int  stage_out[CAP];  // 16KB src sorted by local node
    __shared__ int cntl[BNODES], lofs[BNODES], fill[BNODES], sc[BNODES];

    int b = blockIdx.x, t = threadIdx.x;
    int s0 = b < nb ? boffs[b] : e_cnt;
    int s1 = (b + 1 < nb) ? boffs[b + 1] : e_cnt;
    int m = s1 - s0;

    if (t < BNODES) { cntl[t] = 0; fill[t] = 0; }
    __syncthreads();

    // load + local per-node histogram
    for (int i = t; i < m; i += 256) {
        uint pk = ebuf[s0 + i];
        if (i < CAP) stage_in[i] = pk;
        atomicAdd(&cntl[pk >> 17], 1);
    }
    __syncthreads();

    // exclusive scan of 128 local counts
    if (t < BNODES) sc[t] = cntl[t];
    __syncthreads();
#pragma unroll
    for (int off = 1; off < BNODES; off <<= 1) {
        int v = (t < BNODES && t >= off) ? sc[t - off] : 0;
        __syncthreads();
        if (t < BNODES) sc[t] += v;
        __syncthreads();
    }
    if (t < BNODES) {
        lofs[t] = sc[t] - cntl[t];
        int d = (b << BSH) + t;
        if (d < n) node_offs[d] = s0 + lofs[t];
    }
    __syncthreads();

    // placement into LDS (or rare global spill beyond CAP)
    for (int i = t; i < m; i += 256) {
        uint pk = (i < CAP) ? stage_in[i] : ebuf[s0 + i];
        int ln = (int)(pk >> 17);
        int s = (int)(pk & 0x1FFFFu);
        int r = atomicAdd(&fill[ln], 1);
        int pos = lofs[ln] + r;
        if (pos < CAP) stage_out[pos] = s;
        else           esrc[s0 + pos] = s;
    }
    __syncthreads();

    // coalesced writeback
    int lim = min(m, CAP);
    for (int i = t; i < lim; i += 256) esrc[s0 + i] = stage_out[i];
}

// ---------- per-node gather aggregation, ILP-8, register accumulate ----------

__global__ __launch_bounds__(256) void k_agg3(
        const int* __restrict__ esrc, const int* __restrict__ node_offs,
        const float* __restrict__ dinv, const float* __restrict__ proj,
        float* __restrict__ out, int n, int e_cnt) {
    int t = threadIdx.x;
    int j = t & 31, g = t >> 5;
    int d = blockIdx.x * 8 + g;
    if (d >= n) return;
    int start = node_offs[d];
    int end = (d + 1 < n) ? node_offs[d + 1] : e_cnt;
    float acc = 0.0f;
    int k = start;
    for (; k + 8 <= end; k += 8) {
        int s0 = esrc[k + 0], s1 = esrc[k + 1], s2 = esrc[k + 2], s3 = esrc[k + 3];
        int s4 = esrc[k + 4], s5 = esrc[k + 5], s6 = esrc[k + 6], s7 = esrc[k + 7];
        float p0 = proj[((size_t)s0 << 5) + j];
        float p1 = proj[((size_t)s1 << 5) + j];
        float p2 = proj[((size_t)s2 << 5) + j];
        float p3 = proj[((size_t)s3 << 5) + j];
        float p4 = proj[((size_t)s4 << 5) + j];
        float p5 = proj[((size_t)s5 << 5) + j];
        float p6 = proj[((size_t)s6 << 5) + j];
        float p7 = proj[((size_t)s7 << 5) + j];
        acc += ((p0 + p1) + (p2 + p3)) + ((p4 + p5) + (p6 + p7));
    }
    for (; k < end; ++k) acc += proj[((size_t)esrc[k] << 5) + j];
    float add = dinv[d] * acc;
    float* o = (j < DOUT) ? (out + (size_t)d * DOUT + j)
                          : (out + (size_t)n * DOUT + (size_t)d * DOUT + (j - DOUT));
    *o += add;  // exclusive owner, non-atomic
}

// ---------- fallback (round-1 atomic) path ----------

__global__ void k_init_deg(float* __restrict__ deg, int n) {
    int i = blockIdx.x * blockDim.x + threadIdx.x;
    if (i < n) deg[i] = 1.0f;
}

__global__ void k_count(const int* __restrict__ dst, float* __restrict__ deg, int e_cnt) {
    int e = blockIdx.x * blockDim.x + threadIdx.x;
    if (e < e_cnt) unsafeAtomicAdd(&deg[dst[e]], 1.0f);
}

__global__ void k_projF(const float* __restrict__ x,
                        const float* __restrict__ Wmu, const float* __restrict__ bmu,
                        const float* __restrict__ Wls, const float* __restrict__ bls,
                        float* __restrict__ deg_dinv, float* __restrict__ proj,
                        float* __restrict__ out, int n) {
    __shared__ float Ws[DIN * DC];
    __shared__ float bs[DC];
    int t = threadIdx.x;
    for (int idx = t; idx < DIN * DC; idx += blockDim.x) {
        int k = idx >> 5, j = idx & 31;
        Ws[idx] = (j < DOUT) ? Wmu[k * DOUT + j] : Wls[k * DOUT + (j - DOUT)];
    }
    if (t < DC) bs[t] = (t < DOUT) ? bmu[t] : bls[t - DOUT];
    __syncthreads();
    int i = blockIdx.x * blockDim.x + t;
    if (i >= n) return;
    float xr[DIN];
    const float4* xp = reinterpret_cast<const float4*>(x + (size_t)i * DIN);
#pragma unroll
    for (int q = 0; q < DIN / 4; ++q) {
        float4 v = xp[q];
        xr[4 * q + 0] = v.x; xr[4 * q + 1] = v.y;
        xr[4 * q + 2] = v.z; xr[4 * q + 3] = v.w;
    }
    float acc[DC];
#pragma unroll
    for (int j = 0; j < DC; ++j) acc[j] = 0.0f;
#pragma unroll 4
    for (int k = 0; k < DIN; ++k) {
        float xv = xr[k];
#pragma unroll
        for (int j = 0; j < DC; ++j) acc[j] += xv * Ws[k * DC + j];
    }
    float dv = rsqrtf(deg_dinv[i]);
    deg_dinv[i] = dv;
    float d2 = dv * dv;
    float4* pp = reinterpret_cast<float4*>(proj + (size_t)i * DC);
#pragma unroll
    for (int q = 0; q < DC / 4; ++q) {
        float4 v;
        v.x = acc[4 * q + 0]; v.y = acc[4 * q + 1];
        v.z = acc[4 * q + 2]; v.w = acc[4 * q + 3];
        pp[q] = v;
    }
    float* omu = out + (size_t)i * DOUT;
    float* ols = out + (size_t)n * DOUT + (size_t)i * DOUT;
#pragma unroll
    for (int j = 0; j < DOUT; ++j) omu[j] = bs[j] + d2 * acc[j];
#pragma unroll
    for (int j = 0; j < DOUT; ++j) ols[j] = bs[DOUT + j] + d2 * acc[DOUT + j];
}

__global__ void k_scatterF(const int* __restrict__ src, const int* __restrict__ dst,
                           const float* __restrict__ dinv, const float* __restrict__ proj,
                           float* __restrict__ out, int e_cnt, int n) {
    long long gid = (long long)blockIdx.x * blockDim.x + threadIdx.x;
    int e = (int)(gid >> 5);
    int j = (int)(gid & 31);
    if (e >= e_cnt) return;
    int s = src[e], d = dst[e];
    float norm = dinv[s] * dinv[d];
    float v = norm * proj[(size_t)s * DC + j];
    float* o = (j < DOUT) ? (out + (size_t)d * DOUT + j)
                          : (out + (size_t)n * DOUT + (size_t)d * DOUT + (j - DOUT));
    unsafeAtomicAdd(o, v);
}

// ---------- launch ----------

extern "C" void kernel_launch(void* const* d_in, const int* in_sizes, int n_in,
                              void* d_out, int out_size, void* d_ws, size_t ws_size,
                              hipStream_t stream) {
    const float* x   = (const float*)d_in[0];
    const int*   ei  = (const int*)d_in[1];
    const float* Wmu = (const float*)d_in[2];
    const float* bmu = (const float*)d_in[3];
    const float* Wls = (const float*)d_in[4];
    const float* bls = (const float*)d_in[5];
    float* out = (float*)d_out;

    int n = in_sizes[0] / DIN;       // 100000
    int e_cnt = in_sizes[1] / 2;     // 1600000
    const int* src = ei;
    const int* dst = ei + e_cnt;

    int nb = (n + BNODES - 1) >> BSH;   // 782 buckets
    bool pack_ok = (n <= (1 << 17));

    size_t need = (size_t)n * 4           /* cnt       */
                + (size_t)n * 4           /* dinv      */
                + (size_t)n * DC * 4      /* proj      */
                + (size_t)n * 4           /* node_offs */
                + (size_t)NBP * 4 * 3     /* bsum, boffs, bfill */
                + (size_t)e_cnt * 4       /* ebuf      */
                + (size_t)e_cnt * 4;      /* esrc      */

    int nblk = (n + 255) / 256;
    int eblk = (e_cnt + 255) / 256;

    if (nb <= NBP && pack_ok && ws_size >= need) {
        char* w = (char*)d_ws;
        int*   cnt   = (int*)w;    w += (size_t)n * 4;
        float* dinv  = (float*)w;  w += (size_t)n * 4;
        float* proj  = (float*)w;  w += (size_t)n * DC * 4;
        int*   noffs = (int*)w;    w += (size_t)n * 4;
        int*   bsum  = (int*)w;    w += NBP * 4;
        int*   boffs = (int*)w;    w += NBP * 4;
        int*   bfill = (int*)w;    w += NBP * 4;
        uint*  ebuf  = (uint*)w;   w += (size_t)e_cnt * 4;
        int*   esrc  = (int*)w;

        k_zero_cnt<<<nblk, 256, 0, stream>>>(cnt, n);
        k_hist<<<eblk, 256, 0, stream>>>(dst, cnt, e_cnt);
        k_proj2<<<nblk, 256, 0, stream>>>(x, Wmu, bmu, Wls, bls, cnt, dinv, proj, out, n);
        k_bsum<<<nb, 128, 0, stream>>>(cnt, bsum, n);
        k_bscan<<<1, NBP, 0, stream>>>(bsum, boffs, bfill, nb);
        int binblk = (e_cnt + EPB - 1) / EPB;
        k_bin<<<binblk, TPB_BIN, 0, stream>>>(src, dst, boffs, bfill, ebuf, e_cnt, nb);
        k_sortb<<<nb, 256, 0, stream>>>(ebuf, boffs, noffs, esrc, n, e_cnt, nb);
        k_agg3<<<(n + 7) / 8, 256, 0, stream>>>(esrc, noffs, dinv, proj, out, n, e_cnt);
    } else {
        float* deg  = (float*)d_ws;
        float* proj = deg + n;
        k_init_deg<<<nblk, 256, 0, stream>>>(deg, n);
        k_count<<<eblk, 256, 0, stream>>>(dst, deg, e_cnt);
        k_projF<<<nblk, 256, 0, stream>>>(x, Wmu, bmu, Wls, bls, deg, proj, out, n);
        long long tasks = (long long)e_cnt * DC;
        k_scatterF<<<(int)((tasks + 255) / 256), 256, 0, stream>>>(src, dst, deg, proj, out, e_cnt, n);
    }
}

// Round 5
// 112.389 us; speedup vs baseline: 4.2512x; 1.5330x over previous
//
#include <hip/hip_runtime.h>

#define DIN 48
#define DOUT 16
#define DC 32      // combined output dims: [mu(16) | logstd(16)]
#define BSH 7      // bucket shift: 128 nodes per bucket
#define BNODES 128
#define NBP 1024   // padded bucket count (power of 2, >= nb)
#define EPB 8192   // edges per binning block
#define TPB_BIN 1024
#define EPB2 16384 // edges per bucket-count block
#define CAP 4096   // max staged edges per bucket in k_sortb

typedef unsigned int uint;

// ---------- bucket-level histogram: LDS-privatized, ~77k global atomics ----------

__global__ __launch_bounds__(1024) void k_bcount(const int* __restrict__ dst,
                                                 int* __restrict__ bsum, int e_cnt) {
    __shared__ int h[NBP];
    int t = threadIdx.x;
    h[t] = 0;
    __syncthreads();
    int e0 = blockIdx.x * EPB2;
    int ec = min(EPB2, e_cnt - e0);
    for (int k = t; k < ec; k += 1024) atomicAdd(&h[dst[e0 + k] >> BSH], 1);
    __syncthreads();
    int v = h[t];
    if (v) atomicAdd(&bsum[t], v);
}

// single-block exclusive scan of <=1024 bucket sums; also zero bfill
__global__ void k_bscan(const int* __restrict__ bsum, int* __restrict__ boffs,
                        int* __restrict__ bfill, int nb) {
    __shared__ int sd[NBP];
    int t = threadIdx.x;
    int v = (t < nb) ? bsum[t] : 0;
    sd[t] = v;
    __syncthreads();
#pragma unroll
    for (int off = 1; off < NBP; off <<= 1) {
        int x = (t >= off) ? sd[t - off] : 0;
        __syncthreads();
        sd[t] += x;
        __syncthreads();
    }
    if (t < nb) { boffs[t] = sd[t] - v; bfill[t] = 0; }
}

// ---------- binning: stage edges bucket-sorted in LDS, write contiguous runs ----------

__global__ __launch_bounds__(TPB_BIN) void k_bin(
        const int* __restrict__ src, const int* __restrict__ dst,
        const int* __restrict__ boffs, int* __restrict__ bfill,
        uint* __restrict__ ebuf, int e_cnt, int nb) {
    __shared__ uint stageV[EPB];              // 32KB (also scan temp)
    __shared__ unsigned short stageB[EPB];    // 16KB
    __shared__ int hist[NBP];                 // 4KB (reused as local fill)
    __shared__ int lofs[NBP];                 // 4KB
    __shared__ int gbase[NBP];                // 4KB

    int t = threadIdx.x;
    int e0 = blockIdx.x * EPB;
    int ec = min(EPB, e_cnt - e0);

    hist[t] = 0;
    __syncthreads();
    for (int k = t; k < ec; k += TPB_BIN) atomicAdd(&hist[dst[e0 + k] >> BSH], 1);
    __syncthreads();
    {
        int v = hist[t];
        uint* sd = stageV;
        sd[t] = (uint)v;
        __syncthreads();
#pragma unroll
        for (int off = 1; off < NBP; off <<= 1) {
            uint x = (t >= off) ? sd[t - off] : 0u;
            __syncthreads();
            sd[t] += x;
            __syncthreads();
        }
        lofs[t] = (int)sd[t] - v;
    }
    if (t < nb) {
        int h = hist[t];
        if (h > 0) gbase[t] = atomicAdd(&bfill[t], h);
    }
    __syncthreads();
    hist[t] = 0;
    __syncthreads();
    for (int k = t; k < ec; k += TPB_BIN) {
        int d = dst[e0 + k], s = src[e0 + k];
        int b = d >> BSH;
        int p = atomicAdd(&hist[b], 1);
        int idx = lofs[b] + p;
        stageV[idx] = ((uint)(d & (BNODES - 1)) << 17) | (uint)s;
        stageB[idx] = (unsigned short)b;
    }
    __syncthreads();
    for (int i = t; i < ec; i += TPB_BIN) {
        int b = stageB[i];
        int gpos = boffs[b] + gbase[b] + (i - lofs[b]);
        ebuf[gpos] = stageV[i];
    }
}

// ---------- per-bucket node sort: bucket CSR -> node CSR + dinv, coalesced ----------

__global__ __launch_bounds__(256) void k_sortb(
        const uint* __restrict__ ebuf, const int* __restrict__ boffs,
        int* __restrict__ node_offs, int* __restrict__ esrc,
        float* __restrict__ dinv, int n, int e_cnt, int nb) {
    __shared__ uint stage_in[CAP];   // 16KB raw packed entries
    __shared__ int  stage_out[CAP];  // 16KB src sorted by local node
    __shared__ int cntl[BNODES], lofs[BNODES], fill[BNODES], sc[BNODES];

    int b = blockIdx.x, t = threadIdx.x;
    int s0 = b < nb ? boffs[b] : e_cnt;
    int s1 = (b + 1 < nb) ? boffs[b + 1] : e_cnt;
    int m = s1 - s0;

    if (t < BNODES) { cntl[t] = 0; fill[t] = 0; }
    __syncthreads();

    // load + local per-node histogram
    for (int i = t; i < m; i += 256) {
        uint pk = ebuf[s0 + i];
        if (i < CAP) stage_in[i] = pk;
        atomicAdd(&cntl[pk >> 17], 1);
    }
    __syncthreads();

    // exclusive scan of 128 local counts
    if (t < BNODES) sc[t] = cntl[t];
    __syncthreads();
#pragma unroll
    for (int off = 1; off < BNODES; off <<= 1) {
        int v = (t < BNODES && t >= off) ? sc[t - off] : 0;
        __syncthreads();
        if (t < BNODES) sc[t] += v;
        __syncthreads();
    }
    if (t < BNODES) {
        lofs[t] = sc[t] - cntl[t];
        int d = (b << BSH) + t;
        if (d < n) {
            node_offs[d] = s0 + lofs[t];
            dinv[d] = rsqrtf(1.0f + (float)cntl[t]);
        }
    }
    __syncthreads();

    // placement into LDS (or rare global spill beyond CAP)
    for (int i = t; i < m; i += 256) {
        uint pk = (i < CAP) ? stage_in[i] : ebuf[s0 + i];
        int ln = (int)(pk >> 17);
        int s = (int)(pk & 0x1FFFFu);
        int r = atomicAdd(&fill[ln], 1);
        int pos = lofs[ln] + r;
        if (pos < CAP) stage_out[pos] = s;
        else           esrc[s0 + pos] = s;
    }
    __syncthreads();

    // coalesced writeback
    int lim = min(m, CAP);
    for (int i = t; i < lim; i += 256) esrc[s0 + i] = stage_out[i];
}

// ---------- projection (proj_scaled = dinv * x@[Wmu|Wls]; out = self term) ----------

__global__ void k_proj2(const float* __restrict__ x,
                        const float* __restrict__ Wmu, const float* __restrict__ bmu,
                        const float* __restrict__ Wls, const float* __restrict__ bls,
                        const float* __restrict__ dinv, float* __restrict__ proj,
                        float* __restrict__ out, int n) {
    __shared__ float Ws[DIN * DC];
    __shared__ float bs[DC];
    int t = threadIdx.x;
    for (int idx = t; idx < DIN * DC; idx += blockDim.x) {
        int k = idx >> 5, j = idx & 31;
        Ws[idx] = (j < DOUT) ? Wmu[k * DOUT + j] : Wls[k * DOUT + (j - DOUT)];
    }
    if (t < DC) bs[t] = (t < DOUT) ? bmu[t] : bls[t - DOUT];
    __syncthreads();

    int i = blockIdx.x * blockDim.x + t;
    if (i >= n) return;

    float xr[DIN];
    const float4* xp = reinterpret_cast<const float4*>(x + (size_t)i * DIN);
#pragma unroll
    for (int q = 0; q < DIN / 4; ++q) {
        float4 v = xp[q];
        xr[4 * q + 0] = v.x; xr[4 * q + 1] = v.y;
        xr[4 * q + 2] = v.z; xr[4 * q + 3] = v.w;
    }

    float acc[DC];
#pragma unroll
    for (int j = 0; j < DC; ++j) acc[j] = 0.0f;
#pragma unroll 4
    for (int k = 0; k < DIN; ++k) {
        float xv = xr[k];
#pragma unroll
        for (int j = 0; j < DC; ++j) acc[j] += xv * Ws[k * DC + j];
    }

    float dv = dinv[i];

    float4* pp = reinterpret_cast<float4*>(proj + (size_t)i * DC);
#pragma unroll
    for (int q = 0; q < DC / 4; ++q) {
        float4 v;
        v.x = dv * acc[4 * q + 0]; v.y = dv * acc[4 * q + 1];
        v.z = dv * acc[4 * q + 2]; v.w = dv * acc[4 * q + 3];
        pp[q] = v;
    }

    float d2 = dv * dv;
    float* omu = out + (size_t)i * DOUT;
    float* ols = out + (size_t)n * DOUT + (size_t)i * DOUT;
#pragma unroll
    for (int j = 0; j < DOUT; ++j) omu[j] = bs[j] + d2 * acc[j];
#pragma unroll
    for (int j = 0; j < DOUT; ++j) ols[j] = bs[DOUT + j] + d2 * acc[DOUT + j];
}

// ---------- per-node gather aggregation, ILP-8, register accumulate ----------

__global__ __launch_bounds__(256) void k_agg3(
        const int* __restrict__ esrc, const int* __restrict__ node_offs,
        const float* __restrict__ dinv, const float* __restrict__ proj,
        float* __restrict__ out, int n, int e_cnt) {
    int t = threadIdx.x;
    int j = t & 31, g = t >> 5;
    int d = blockIdx.x * 8 + g;
    if (d >= n) return;
    int start = node_offs[d];
    int end = (d + 1 < n) ? node_offs[d + 1] : e_cnt;
    float acc = 0.0f;
    int k = start;
    for (; k + 8 <= end; k += 8) {
        int s0 = esrc[k + 0], s1 = esrc[k + 1], s2 = esrc[k + 2], s3 = esrc[k + 3];
        int s4 = esrc[k + 4], s5 = esrc[k + 5], s6 = esrc[k + 6], s7 = esrc[k + 7];
        float p0 = proj[((size_t)s0 << 5) + j];
        float p1 = proj[((size_t)s1 << 5) + j];
        float p2 = proj[((size_t)s2 << 5) + j];
        float p3 = proj[((size_t)s3 << 5) + j];
        float p4 = proj[((size_t)s4 << 5) + j];
        float p5 = proj[((size_t)s5 << 5) + j];
        float p6 = proj[((size_t)s6 << 5) + j];
        float p7 = proj[((size_t)s7 << 5) + j];
        acc += ((p0 + p1) + (p2 + p3)) + ((p4 + p5) + (p6 + p7));
    }
    for (; k < end; ++k) acc += proj[((size_t)esrc[k] << 5) + j];
    float add = dinv[d] * acc;
    float* o = (j < DOUT) ? (out + (size_t)d * DOUT + j)
                          : (out + (size_t)n * DOUT + (size_t)d * DOUT + (j - DOUT));
    *o += add;  // exclusive owner, non-atomic
}

// ---------- fallback (round-1 atomic) path ----------

__global__ void k_init_deg(float* __restrict__ deg, int n) {
    int i = blockIdx.x * blockDim.x + threadIdx.x;
    if (i < n) deg[i] = 1.0f;
}

__global__ void k_count(const int* __restrict__ dst, float* __restrict__ deg, int e_cnt) {
    int e = blockIdx.x * blockDim.x + threadIdx.x;
    if (e < e_cnt) unsafeAtomicAdd(&deg[dst[e]], 1.0f);
}

__global__ void k_projF(const float* __restrict__ x,
                        const float* __restrict__ Wmu, const float* __restrict__ bmu,
                        const float* __restrict__ Wls, const float* __restrict__ bls,
                        float* __restrict__ deg_dinv, float* __restrict__ proj,
                        float* __restrict__ out, int n) {
    __shared__ float Ws[DIN * DC];
    __shared__ float bs[DC];
    int t = threadIdx.x;
    for (int idx = t; idx < DIN * DC; idx += blockDim.x) {
        int k = idx >> 5, j = idx & 31;
        Ws[idx] = (j < DOUT) ? Wmu[k * DOUT + j] : Wls[k * DOUT + (j - DOUT)];
    }
    if (t < DC) bs[t] = (t < DOUT) ? bmu[t] : bls[t - DOUT];
    __syncthreads();
    int i = blockIdx.x * blockDim.x + t;
    if (i >= n) return;
    float xr[DIN];
    const float4* xp = reinterpret_cast<const float4*>(x + (size_t)i * DIN);
#pragma unroll
    for (int q = 0; q < DIN / 4; ++q) {
        float4 v = xp[q];
        xr[4 * q + 0] = v.x; xr[4 * q + 1] = v.y;
        xr[4 * q + 2] = v.z; xr[4 * q + 3] = v.w;
    }
    float acc[DC];
#pragma unroll
    for (int j = 0; j < DC; ++j) acc[j] = 0.0f;
#pragma unroll 4
    for (int k = 0; k < DIN; ++k) {
        float xv = xr[k];
#pragma unroll
        for (int j = 0; j < DC; ++j) acc[j] += xv * Ws[k * DC + j];
    }
    float dv = rsqrtf(deg_dinv[i]);
    deg_dinv[i] = dv;
    float d2 = dv * dv;
    float4* pp = reinterpret_cast<float4*>(proj + (size_t)i * DC);
#pragma unroll
    for (int q = 0; q < DC / 4; ++q) {
        float4 v;
        v.x = acc[4 * q + 0]; v.y = acc[4 * q + 1];
        v.z = acc[4 * q + 2]; v.w = acc[4 * q + 3];
        pp[q] = v;
    }
    float* omu = out + (size_t)i * DOUT;
    float* ols = out + (size_t)n * DOUT + (size_t)i * DOUT;
#pragma unroll
    for (int j = 0; j < DOUT; ++j) omu[j] = bs[j] + d2 * acc[j];
#pragma unroll
    for (int j = 0; j < DOUT; ++j) ols[j] = bs[DOUT + j] + d2 * acc[DOUT + j];
}

__global__ void k_scatterF(const int* __restrict__ src, const int* __restrict__ dst,
                           const float* __restrict__ dinv, const float* __restrict__ proj,
                           float* __restrict__ out, int e_cnt, int n) {
    long long gid = (long long)blockIdx.x * blockDim.x + threadIdx.x;
    int e = (int)(gid >> 5);
    int j = (int)(gid & 31);
    if (e >= e_cnt) return;
    int s = src[e], d = dst[e];
    float norm = dinv[s] * dinv[d];
    float v = norm * proj[(size_t)s * DC + j];
    float* o = (j < DOUT) ? (out + (size_t)d * DOUT + j)
                          : (out + (size_t)n * DOUT + (size_t)d * DOUT + (j - DOUT));
    unsafeAtomicAdd(o, v);
}

// ---------- launch ----------

extern "C" void kernel_launch(void* const* d_in, const int* in_sizes, int n_in,
                              void* d_out, int out_size, void* d_ws, size_t ws_size,
                              hipStream_t stream) {
    const float* x   = (const float*)d_in[0];
    const int*   ei  = (const int*)d_in[1];
    const float* Wmu = (const float*)d_in[2];
    const float* bmu = (const float*)d_in[3];
    const float* Wls = (const float*)d_in[4];
    const float* bls = (const float*)d_in[5];
    float* out = (float*)d_out;

    int n = in_sizes[0] / DIN;       // 100000
    int e_cnt = in_sizes[1] / 2;     // 1600000
    const int* src = ei;
    const int* dst = ei + e_cnt;

    int nb = (n + BNODES - 1) >> BSH;   // 782 buckets
    bool pack_ok = (n <= (1 << 17));

    size_t need = (size_t)n * 4           /* dinv      */
                + (size_t)n * DC * 4      /* proj      */
                + (size_t)n * 4           /* node_offs */
                + (size_t)NBP * 4 * 3     /* bsum, boffs, bfill */
                + (size_t)e_cnt * 4       /* ebuf      */
                + (size_t)e_cnt * 4;      /* esrc      */

    int nblk = (n + 255) / 256;
    int eblk = (e_cnt + 255) / 256;

    if (nb <= NBP && pack_ok && ws_size >= need) {
        char* w = (char*)d_ws;
        float* dinv  = (float*)w;  w += (size_t)n * 4;
        float* proj  = (float*)w;  w += (size_t)n * DC * 4;
        int*   noffs = (int*)w;    w += (size_t)n * 4;
        int*   bsum  = (int*)w;    w += NBP * 4;
        int*   boffs = (int*)w;    w += NBP * 4;
        int*   bfill = (int*)w;    w += NBP * 4;
        uint*  ebuf  = (uint*)w;   w += (size_t)e_cnt * 4;
        int*   esrc  = (int*)w;

        hipMemsetAsync(bsum, 0, NBP * sizeof(int), stream);
        int cblk = (e_cnt + EPB2 - 1) / EPB2;
        k_bcount<<<cblk, 1024, 0, stream>>>(dst, bsum, e_cnt);
        k_bscan<<<1, NBP, 0, stream>>>(bsum, boffs, bfill, nb);
        int binblk = (e_cnt + EPB - 1) / EPB;
        k_bin<<<binblk, TPB_BIN, 0, stream>>>(src, dst, boffs, bfill, ebuf, e_cnt, nb);
        k_sortb<<<nb, 256, 0, stream>>>(ebuf, boffs, noffs, esrc, dinv, n, e_cnt, nb);
        k_proj2<<<nblk, 256, 0, stream>>>(x, Wmu, bmu, Wls, bls, dinv, proj, out, n);
        k_agg3<<<(n + 7) / 8, 256, 0, stream>>>(esrc, noffs, dinv, proj, out, n, e_cnt);
    } else {
        float* deg  = (float*)d_ws;
        float* proj = deg + n;
        k_init_deg<<<nblk, 256, 0, stream>>>(deg, n);
        k_count<<<eblk, 256, 0, stream>>>(dst, deg, e_cnt);
        k_projF<<<nblk, 256, 0, stream>>>(x, Wmu, bmu, Wls, bls, deg, proj, out, n);
        long long tasks = (long long)e_cnt * DC;
        k_scatterF<<<(int)((tasks + 255) / 256), 256, 0, stream>>>(src, dst, deg, proj, out, e_cnt, n);
    }
}

// Round 6
// 99.175 us; speedup vs baseline: 4.8176x; 1.1332x over previous
//
#include <hip/hip_runtime.h>

#define DIN 48
#define DOUT 16
#define DC 32      // combined output dims: [mu(16) | logstd(16)]
#define BSH 7      // bucket shift: 128 nodes per bucket
#define BNODES 128
#define NBP 1024   // padded bucket count (power of 2, >= nb)
#define EPB 8192   // edges per binning block
#define TPB_BIN 1024
#define EPB2 16384 // edges per bucket-count block
#define CAP 4096   // max staged edges per bucket in k_sortb
#define XS 49      // padded LDS stride for x tile (conflict-free)

typedef unsigned int uint;
typedef unsigned short ushort;

__device__ __forceinline__ float b2f(ushort u) {
    union { uint i; float f; } v; v.i = ((uint)u) << 16; return v.f;
}
__device__ __forceinline__ ushort f2b(float f) {
    union { float f; uint i; } v; v.f = f;
    uint b = v.i;
    return (ushort)((b + 0x7FFFu + ((b >> 16) & 1u)) >> 16);  // round-to-nearest-even
}

// ---------- bucket-level histogram: LDS-privatized ----------

__global__ __launch_bounds__(1024) void k_bcount(const int* __restrict__ dst,
                                                 int* __restrict__ bsum, int e_cnt) {
    __shared__ int h[NBP];
    int t = threadIdx.x;
    h[t] = 0;
    __syncthreads();
    int e0 = blockIdx.x * EPB2;
    int ec = min(EPB2, e_cnt - e0);
    for (int k = t; k < ec; k += 1024) atomicAdd(&h[dst[e0 + k] >> BSH], 1);
    __syncthreads();
    int v = h[t];
    if (v) atomicAdd(&bsum[t], v);
}

// single-block exclusive scan of <=1024 bucket sums; also zero bfill
__global__ void k_bscan(const int* __restrict__ bsum, int* __restrict__ boffs,
                        int* __restrict__ bfill, int nb) {
    __shared__ int sd[NBP];
    int t = threadIdx.x;
    int v = (t < nb) ? bsum[t] : 0;
    sd[t] = v;
    __syncthreads();
#pragma unroll
    for (int off = 1; off < NBP; off <<= 1) {
        int x = (t >= off) ? sd[t - off] : 0;
        __syncthreads();
        sd[t] += x;
        __syncthreads();
    }
    if (t < nb) { boffs[t] = sd[t] - v; bfill[t] = 0; }
}

// ---------- binning: stage edges bucket-sorted in LDS, write contiguous runs ----------

__global__ __launch_bounds__(TPB_BIN) void k_bin(
        const int* __restrict__ src, const int* __restrict__ dst,
        const int* __restrict__ boffs, int* __restrict__ bfill,
        uint* __restrict__ ebuf, int e_cnt, int nb) {
    __shared__ uint stageV[EPB];
    __shared__ unsigned short stageB[EPB];
    __shared__ int hist[NBP];
    __shared__ int lofs[NBP];
    __shared__ int gbase[NBP];

    int t = threadIdx.x;
    int e0 = blockIdx.x * EPB;
    int ec = min(EPB, e_cnt - e0);

    hist[t] = 0;
    __syncthreads();
    for (int k = t; k < ec; k += TPB_BIN) atomicAdd(&hist[dst[e0 + k] >> BSH], 1);
    __syncthreads();
    {
        int v = hist[t];
        uint* sd = stageV;
        sd[t] = (uint)v;
        __syncthreads();
#pragma unroll
        for (int off = 1; off < NBP; off <<= 1) {
            uint x = (t >= off) ? sd[t - off] : 0u;
            __syncthreads();
            sd[t] += x;
            __syncthreads();
        }
        lofs[t] = (int)sd[t] - v;
    }
    if (t < nb) {
        int h = hist[t];
        if (h > 0) gbase[t] = atomicAdd(&bfill[t], h);
    }
    __syncthreads();
    hist[t] = 0;
    __syncthreads();
    for (int k = t; k < ec; k += TPB_BIN) {
        int d = dst[e0 + k], s = src[e0 + k];
        int b = d >> BSH;
        int p = atomicAdd(&hist[b], 1);
        int idx = lofs[b] + p;
        stageV[idx] = ((uint)(d & (BNODES - 1)) << 17) | (uint)s;
        stageB[idx] = (unsigned short)b;
    }
    __syncthreads();
    for (int i = t; i < ec; i += TPB_BIN) {
        int b = stageB[i];
        int gpos = boffs[b] + gbase[b] + (i - lofs[b]);
        ebuf[gpos] = stageV[i];
    }
}

// ---------- per-bucket node sort: bucket CSR -> node CSR + dinv ----------

__global__ __launch_bounds__(256) void k_sortb(
        const uint* __restrict__ ebuf, const int* __restrict__ boffs,
        int* __restrict__ node_offs, int* __restrict__ esrc,
        float* __restrict__ dinv, int n, int e_cnt, int nb) {
    __shared__ uint stage_in[CAP];
    __shared__ int  stage_out[CAP];
    __shared__ int cntl[BNODES], lofs[BNODES], fill[BNODES], sc[BNODES];

    int b = blockIdx.x, t = threadIdx.x;
    int s0 = b < nb ? boffs[b] : e_cnt;
    int s1 = (b + 1 < nb) ? boffs[b + 1] : e_cnt;
    int m = s1 - s0;

    if (t < BNODES) { cntl[t] = 0; fill[t] = 0; }
    __syncthreads();

    for (int i = t; i < m; i += 256) {
        uint pk = ebuf[s0 + i];
        if (i < CAP) stage_in[i] = pk;
        atomicAdd(&cntl[pk >> 17], 1);
    }
    __syncthreads();

    if (t < BNODES) sc[t] = cntl[t];
    __syncthreads();
#pragma unroll
    for (int off = 1; off < BNODES; off <<= 1) {
        int v = (t < BNODES && t >= off) ? sc[t - off] : 0;
        __syncthreads();
        if (t < BNODES) sc[t] += v;
        __syncthreads();
    }
    if (t < BNODES) {
        lofs[t] = sc[t] - cntl[t];
        int d = (b << BSH) + t;
        if (d < n) {
            node_offs[d] = s0 + lofs[t];
            dinv[d] = rsqrtf(1.0f + (float)cntl[t]);
        }
    }
    __syncthreads();

    for (int i = t; i < m; i += 256) {
        uint pk = (i < CAP) ? stage_in[i] : ebuf[s0 + i];
        int ln = (int)(pk >> 17);
        int s = (int)(pk & 0x1FFFFu);
        int r = atomicAdd(&fill[ln], 1);
        int pos = lofs[ln] + r;
        if (pos < CAP) stage_out[pos] = s;
        else           esrc[s0 + pos] = s;
    }
    __syncthreads();

    int lim = min(m, CAP);
    for (int i = t; i < lim; i += 256) esrc[s0 + i] = stage_out[i];
}

// ---------- projection, register-tiled 4x4: 128 nodes x 32 cols per block ----------
// proj_h (bf16) = dinv * x@[Wmu|Wls]; out = bias + dinv^2 * (x@W) (self term)

__global__ __launch_bounds__(256) void k_proj3(
        const float* __restrict__ x,
        const float* __restrict__ Wmu, const float* __restrict__ bmu,
        const float* __restrict__ Wls, const float* __restrict__ bls,
        const float* __restrict__ dinv, ushort* __restrict__ proj_h,
        float* __restrict__ out, int n) {
    __shared__ float xl[BNODES * XS];       // 128 x 49 = 25088B
    __shared__ float Wl[DIN * DC];          // 6144B
    __shared__ float bs[DC];

    int t = threadIdx.x;
    int base = blockIdx.x * BNODES;

    // stage W + bias
    for (int idx = t; idx < DIN * DC; idx += 256) {
        int k = idx >> 5, j = idx & 31;
        Wl[idx] = (j < DOUT) ? Wmu[k * DOUT + j] : Wls[k * DOUT + (j - DOUT)];
    }
    if (t < DC) bs[t] = (t < DOUT) ? bmu[t] : bls[t - DOUT];

    // stage x tile: 128 nodes x 48 floats = 1536 float4, 6 per thread
#pragma unroll
    for (int it = 0; it < 6; ++it) {
        int f4 = t + 256 * it;
        int fb = f4 * 4;
        int node = fb / DIN, k = fb % DIN;
        int g = base + node;
        if (g < n) {
            float4 v = *reinterpret_cast<const float4*>(x + (size_t)g * DIN + k);
            float* p = &xl[node * XS + k];
            p[0] = v.x; p[1] = v.y; p[2] = v.z; p[3] = v.w;
        }
    }
    __syncthreads();

    int nc = t & 7;        // col group: cols nc*4 .. nc*4+3
    int nr = t >> 3;       // node group: nodes nr*4 .. nr*4+3
    int c0 = nc * 4;

    float4 acc[4];
#pragma unroll
    for (int m = 0; m < 4; ++m) acc[m] = make_float4(0.f, 0.f, 0.f, 0.f);

#pragma unroll 4
    for (int k = 0; k < DIN; ++k) {
        float4 w = *reinterpret_cast<const float4*>(&Wl[k * DC + c0]);
#pragma unroll
        for (int m = 0; m < 4; ++m) {
            float xv = xl[(nr * 4 + m) * XS + k];
            acc[m].x += xv * w.x;
            acc[m].y += xv * w.y;
            acc[m].z += xv * w.z;
            acc[m].w += xv * w.w;
        }
    }

    float4 bv = *reinterpret_cast<const float4*>(&bs[c0]);
#pragma unroll
    for (int m = 0; m < 4; ++m) {
        int d = base + nr * 4 + m;
        if (d >= n) continue;
        float dv = dinv[d];
        // proj (bf16, pre-scaled by dinv)
        ushort4 ph;
        ph.x = f2b(dv * acc[m].x); ph.y = f2b(dv * acc[m].y);
        ph.z = f2b(dv * acc[m].z); ph.w = f2b(dv * acc[m].w);
        *reinterpret_cast<ushort4*>(proj_h + ((size_t)d << 5) + c0) = ph;
        // out self-loop term
        float d2 = dv * dv;
        float4 ov;
        ov.x = bv.x + d2 * acc[m].x; ov.y = bv.y + d2 * acc[m].y;
        ov.z = bv.z + d2 * acc[m].z; ov.w = bv.w + d2 * acc[m].w;
        float* o = (nc < 4) ? (out + (size_t)d * DOUT + c0)
                            : (out + (size_t)n * DOUT + (size_t)d * DOUT + (c0 - DOUT));
        *reinterpret_cast<float4*>(o) = ov;
    }
}

// ---------- per-node gather aggregation (bf16 proj), ILP-8 ----------

__global__ __launch_bounds__(256) void k_agg3(
        const int* __restrict__ esrc, const int* __restrict__ node_offs,
        const float* __restrict__ dinv, const ushort* __restrict__ proj_h,
        float* __restrict__ out, int n, int e_cnt) {
    int t = threadIdx.x;
    int j = t & 31, g = t >> 5;
    int d = blockIdx.x * 8 + g;
    if (d >= n) return;
    int start = node_offs[d];
    int end = (d + 1 < n) ? node_offs[d + 1] : e_cnt;
    float acc = 0.0f;
    int k = start;
    for (; k + 8 <= end; k += 8) {
        int s0 = esrc[k + 0], s1 = esrc[k + 1], s2 = esrc[k + 2], s3 = esrc[k + 3];
        int s4 = esrc[k + 4], s5 = esrc[k + 5], s6 = esrc[k + 6], s7 = esrc[k + 7];
        ushort p0 = proj_h[((size_t)s0 << 5) + j];
        ushort p1 = proj_h[((size_t)s1 << 5) + j];
        ushort p2 = proj_h[((size_t)s2 << 5) + j];
        ushort p3 = proj_h[((size_t)s3 << 5) + j];
        ushort p4 = proj_h[((size_t)s4 << 5) + j];
        ushort p5 = proj_h[((size_t)s5 << 5) + j];
        ushort p6 = proj_h[((size_t)s6 << 5) + j];
        ushort p7 = proj_h[((size_t)s7 << 5) + j];
        acc += ((b2f(p0) + b2f(p1)) + (b2f(p2) + b2f(p3)))
             + ((b2f(p4) + b2f(p5)) + (b2f(p6) + b2f(p7)));
    }
    for (; k < end; ++k) acc += b2f(proj_h[((size_t)esrc[k] << 5) + j]);
    float add = dinv[d] * acc;
    float* o = (j < DOUT) ? (out + (size_t)d * DOUT + j)
                          : (out + (size_t)n * DOUT + (size_t)d * DOUT + (j - DOUT));
    *o += add;  // exclusive owner, non-atomic
}

// ---------- fallback (round-1 atomic) path ----------

__global__ void k_init_deg(float* __restrict__ deg, int n) {
    int i = blockIdx.x * blockDim.x + threadIdx.x;
    if (i < n) deg[i] = 1.0f;
}

__global__ void k_count(const int* __restrict__ dst, float* __restrict__ deg, int e_cnt) {
    int e = blockIdx.x * blockDim.x + threadIdx.x;
    if (e < e_cnt) unsafeAtomicAdd(&deg[dst[e]], 1.0f);
}

__global__ void k_projF(const float* __restrict__ x,
                        const float* __restrict__ Wmu, const float* __restrict__ bmu,
                        const float* __restrict__ Wls, const float* __restrict__ bls,
                        float* __restrict__ deg_dinv, float* __restrict__ proj,
                        float* __restrict__ out, int n) {
    __shared__ float Ws[DIN * DC];
    __shared__ float bs[DC];
    int t = threadIdx.x;
    for (int idx = t; idx < DIN * DC; idx += blockDim.x) {
        int k = idx >> 5, j = idx & 31;
        Ws[idx] = (j < DOUT) ? Wmu[k * DOUT + j] : Wls[k * DOUT + (j - DOUT)];
    }
    if (t < DC) bs[t] = (t < DOUT) ? bmu[t] : bls[t - DOUT];
    __syncthreads();
    int i = blockIdx.x * blockDim.x + t;
    if (i >= n) return;
    float xr[DIN];
    const float4* xp = reinterpret_cast<const float4*>(x + (size_t)i * DIN);
#pragma unroll
    for (int q = 0; q < DIN / 4; ++q) {
        float4 v = xp[q];
        xr[4 * q + 0] = v.x; xr[4 * q + 1] = v.y;
        xr[4 * q + 2] = v.z; xr[4 * q + 3] = v.w;
    }
    float acc[DC];
#pragma unroll
    for (int j = 0; j < DC; ++j) acc[j] = 0.0f;
#pragma unroll 4
    for (int k = 0; k < DIN; ++k) {
        float xv = xr[k];
#pragma unroll
        for (int j = 0; j < DC; ++j) acc[j] += xv * Ws[k * DC + j];
    }
    float dv = rsqrtf(deg_dinv[i]);
    deg_dinv[i] = dv;
    float d2 = dv * dv;
    float4* pp = reinterpret_cast<float4*>(proj + (size_t)i * DC);
#pragma unroll
    for (int q = 0; q < DC / 4; ++q) {
        float4 v;
        v.x = acc[4 * q + 0]; v.y = acc[4 * q + 1];
        v.z = acc[4 * q + 2]; v.w = acc[4 * q + 3];
        pp[q] = v;
    }
    float* omu = out + (size_t)i * DOUT;
    float* ols = out + (size_t)n * DOUT + (size_t)i * DOUT;
#pragma unroll
    for (int j = 0; j < DOUT; ++j) omu[j] = bs[j] + d2 * acc[j];
#pragma unroll
    for (int j = 0; j < DOUT; ++j) ols[j] = bs[DOUT + j] + d2 * acc[DOUT + j];
}

__global__ void k_scatterF(const int* __restrict__ src, const int* __restrict__ dst,
                           const float* __restrict__ dinv, const float* __restrict__ proj,
                           float* __restrict__ out, int e_cnt, int n) {
    long long gid = (long long)blockIdx.x * blockDim.x + threadIdx.x;
    int e = (int)(gid >> 5);
    int j = (int)(gid & 31);
    if (e >= e_cnt) return;
    int s = src[e], d = dst[e];
    float norm = dinv[s] * dinv[d];
    float v = norm * proj[(size_t)s * DC + j];
    float* o = (j < DOUT) ? (out + (size_t)d * DOUT + j)
                          : (out + (size_t)n * DOUT + (size_t)d * DOUT + (j - DOUT));
    unsafeAtomicAdd(o, v);
}

// ---------- launch ----------

extern "C" void kernel_launch(void* const* d_in, const int* in_sizes, int n_in,
                              void* d_out, int out_size, void* d_ws, size_t ws_size,
                              hipStream_t stream) {
    const float* x   = (const float*)d_in[0];
    const int*   ei  = (const int*)d_in[1];
    const float* Wmu = (const float*)d_in[2];
    const float* bmu = (const float*)d_in[3];
    const float* Wls = (const float*)d_in[4];
    const float* bls = (const float*)d_in[5];
    float* out = (float*)d_out;

    int n = in_sizes[0] / DIN;       // 100000
    int e_cnt = in_sizes[1] / 2;     // 1600000
    const int* src = ei;
    const int* dst = ei + e_cnt;

    int nb = (n + BNODES - 1) >> BSH;   // 782 buckets
    bool pack_ok = (n <= (1 << 17));

    size_t need = (size_t)n * 4           /* dinv      */
                + (size_t)n * 4           /* node_offs */
                + (size_t)NBP * 4 * 3     /* bsum, boffs, bfill */
                + (size_t)e_cnt * 4       /* ebuf      */
                + (size_t)e_cnt * 4       /* esrc      */
                + (size_t)n * DC * 2;     /* proj_h    */

    int nblk = (n + 255) / 256;
    int eblk = (e_cnt + 255) / 256;

    if (nb <= NBP && pack_ok && ws_size >= need) {
        char* w = (char*)d_ws;
        float*  dinv  = (float*)w;   w += (size_t)n * 4;
        int*    noffs = (int*)w;     w += (size_t)n * 4;
        int*    bsum  = (int*)w;     w += NBP * 4;
        int*    boffs = (int*)w;     w += NBP * 4;
        int*    bfill = (int*)w;     w += NBP * 4;
        uint*   ebuf  = (uint*)w;    w += (size_t)e_cnt * 4;
        int*    esrc  = (int*)w;     w += (size_t)e_cnt * 4;
        ushort* projh = (ushort*)w;

        hipMemsetAsync(bsum, 0, NBP * sizeof(int), stream);
        int cblk = (e_cnt + EPB2 - 1) / EPB2;
        k_bcount<<<cblk, 1024, 0, stream>>>(dst, bsum, e_cnt);
        k_bscan<<<1, NBP, 0, stream>>>(bsum, boffs, bfill, nb);
        int binblk = (e_cnt + EPB - 1) / EPB;
        k_bin<<<binblk, TPB_BIN, 0, stream>>>(src, dst, boffs, bfill, ebuf, e_cnt, nb);
        k_sortb<<<nb, 256, 0, stream>>>(ebuf, boffs, noffs, esrc, dinv, n, e_cnt, nb);
        k_proj3<<<nb, 256, 0, stream>>>(x, Wmu, bmu, Wls, bls, dinv, projh, out, n);
        k_agg3<<<(n + 7) / 8, 256, 0, stream>>>(esrc, noffs, dinv, projh, out, n, e_cnt);
    } else {
        float* deg  = (float*)d_ws;
        float* proj = deg + n;
        k_init_deg<<<nblk, 256, 0, stream>>>(deg, n);
        k_count<<<eblk, 256, 0, stream>>>(dst, deg, e_cnt);
        k_projF<<<nblk, 256, 0, stream>>>(x, Wmu, bmu, Wls, bls, deg, proj, out, n);
        long long tasks = (long long)e_cnt * DC;
        k_scatterF<<<(int)((tasks + 255) / 256), 256, 0, stream>>>(src, dst, deg, proj, out, e_cnt, n);
    }
}